// Round 7
// baseline (914.050 us; speedup 1.0000x reference)
//
#include <hip/hip_runtime.h>
#include <cstdint>
#include <cstddef>

// Problem constants
#define C_ 256
#define HW_ 4096
#define N_ 131072          // B*H*W = 32*64*64
#define K_ 1024
#define VQ_OFF   33554432  // after z_q (32*256*64*64)
#define IDX_OFF  33554433
#define TOPO_OFF 33685505  // IDX_OFF + 131072
#define VQ_SCALE (1.25f / 33554432.0f)   // (1+0.25) * mean over B*H*W*C elements
#define REFINE_TAU 4e-3f   // unnormalized-dot gap below which we np-emulate (round-3 proven)
#define MARK 2048          // idx marker for flagged pixels (true idx < 1024)

typedef _Float16 half8  __attribute__((ext_vector_type(8)));
typedef float    f32x16 __attribute__((ext_vector_type(16)));
typedef float    f32x4  __attribute__((ext_vector_type(4)));

// Workspace layout (floats):
//   wT  @ 0        [256][1024] fp32  (column-major codebook, for topo/refine)
//   wN  @ 262144   [1024][256] fp32  (row-major codebook, for z_q gather)
//   cbH @ 524288   f16 hi plane in MFMA-fragment-linear order (512 KB)
//   cbL @ 655360   f16 lo plane (512 KB)
// total 3 MB of d_ws.
// Fragment order: idx = ((cw>>5)*16 + (c>>4))*64 + (cw&31) + 32*((c>>3)&1),
// element i = c&7  -> a wave's A-fragment load is cb[(W*16+ks)*64 + lane],
// one fully-coalesced 1KB dwordx4 per wave.

// fp32 multiply with an anti-contraction barrier: numpy rounds x*x BEFORE the
// pairwise add; fp-contract would fuse mul+add into fma (different rounding).
__device__ __forceinline__ float mul_nofuse(float a, float b) {
    float t = a * b;
    asm volatile("" : "+v"(t));
    return t;
}

// numpy pairwise_sum of squares, n=128 (8-accumulator unroll, numpy combine order)
__device__ __forceinline__ float np_sumsq128(const float* x) {
    float r[8];
    #pragma unroll
    for (int j = 0; j < 8; j++) r[j] = mul_nofuse(x[j], x[j]);
    for (int i = 8; i < 128; i += 8) {
        #pragma unroll
        for (int j = 0; j < 8; j++) r[j] += mul_nofuse(x[i + j], x[i + j]);
    }
    return ((r[0] + r[1]) + (r[2] + r[3])) + ((r[4] + r[5]) + (r[6] + r[7]));
}

__device__ __forceinline__ float np_norm256(const float* x) {
    float ss = np_sumsq128(x) + np_sumsq128(x + 128);
    return sqrtf(ss);
}

// async global->LDS, 16B per lane. dest: wave-uniform base (+ lane*16 by HW).
__device__ __forceinline__ void stage16(const half8* g, half8* l) {
    __builtin_amdgcn_global_load_lds(
        (const __attribute__((address_space(1))) void*)g,
        (__attribute__((address_space(3))) void*)l, 16, 0, 0);
}

// Normalize codebook rows (numpy-emulated norms, true division).
// Emits: wT[c][k] fp32, wN[k][c] fp32, and f16 hi/lo fragment planes for MFMA.
__global__ __launch_bounds__(256)
void k_normw(const float* __restrict__ w, float* __restrict__ wT,
             float* __restrict__ wN, half8* __restrict__ cbH,
             half8* __restrict__ cbL, float* __restrict__ out) {
    __shared__ float lw[64][257];
    __shared__ float nrm_sh[64];
    int tid = threadIdx.x;
    if (blockIdx.x == 0 && tid == 0) {
        out[VQ_OFF] = 0.0f;
        out[TOPO_OFF] = 0.0f;
    }
    int r0 = blockIdx.x << 6;
    #pragma unroll
    for (int it = 0; it < 64; it++) {
        int f = (it << 8) + tid;       // 0..16383
        int row = f >> 8, c = f & 255;
        lw[row][c] = w[((size_t)(r0 + row) << 8) + c];
    }
    __syncthreads();
    if (tid < 64) nrm_sh[tid] = fmaxf(np_norm256(&lw[tid][0]), 1e-12f);
    __syncthreads();
    int rr = tid & 63, cg = tid >> 6;
    float nr = nrm_sh[rr];
    for (int c = cg; c < C_; c += 4) {
        wT[(c << 10) + r0 + rr] = lw[rr][c] / nr;
    }
    // wN row-major + f16 fragment planes (hi = f16(v), lo = f16(v - hi))
    int cw = r0 + rr;
    int cwblk = cw >> 5, lrow = cw & 31;
    #pragma unroll
    for (int o8 = cg; o8 < 32; o8 += 4) {   // 8 octets of channels per thread
        int c0 = o8 << 3;
        half8 H, L;
        float vv[8];
        #pragma unroll
        for (int i = 0; i < 8; i++) {
            float v = lw[rr][c0 + i] / nr;
            vv[i] = v;
            _Float16 hh = (_Float16)v;      // RNE
            H[i] = hh;
            L[i] = (_Float16)(v - (float)hh);
        }
        float4* wnp = reinterpret_cast<float4*>(wN + ((size_t)cw << 8) + c0);
        wnp[0] = make_float4(vv[0], vv[1], vv[2], vv[3]);
        wnp[1] = make_float4(vv[4], vv[5], vv[6], vv[7]);
        int fidx = ((cwblk << 4) + (o8 >> 1)) * 64 + lrow + ((o8 & 1) << 5);
        cbH[fidx] = H;
        cbL[fidx] = L;
    }
}

// Topology smoothness loss over the 32x32 grid of normalized codewords.
__global__ void k_topo(const float* __restrict__ wT, float* __restrict__ out) {
    const float W12 = 0.35f / (32.0f * 31.0f * 256.0f);
    const float W34 = 0.35f / (32.0f * 256.0f);
    float acc = 0.0f;
    int base = (blockIdx.x << 8) + threadIdx.x;
    #pragma unroll
    for (int i = 0; i < 4; i++) {
        int e = base + (i << 16);      // e = c*1024 + k, coalesced over wT
        int k = e & 1023;
        int ii = k >> 5, jj = k & 31;
        float v = wT[e];
        if (jj < 31)  { float d = wT[e + 1]   - v; acc += d * d * W12; }
        if (ii < 31)  { float d = wT[e + 32]  - v; acc += d * d * W12; }
        if (jj == 31) { float d = wT[e - 31]  - v; acc += d * d * W34; }
        if (ii == 31) { float d = wT[e - 992] - v; acc += d * d * W34; }
    }
    for (int off = 32; off > 0; off >>= 1) acc += __shfl_xor(acc, off);
    __shared__ float red[4];
    if ((threadIdx.x & 63) == 0) red[threadIdx.x >> 6] = acc;
    __syncthreads();
    if (threadIdx.x == 0) atomicAdd(out + TOPO_OFF, red[0] + red[1] + red[2] + red[3]);
}

// 16-value tree max (all literal indices).
__device__ __forceinline__ float max16(const f32x16& a) {
    float m0 = fmaxf(fmaxf(a[0], a[1]),  fmaxf(a[2], a[3]));
    float m1 = fmaxf(fmaxf(a[4], a[5]),  fmaxf(a[6], a[7]));
    float m2 = fmaxf(fmaxf(a[8], a[9]),  fmaxf(a[10], a[11]));
    float m3 = fmaxf(fmaxf(a[12], a[13]), fmaxf(a[14], a[15]));
    return fmaxf(fmaxf(m0, m1), fmaxf(m2, m3));
}

// Fold one 32x32 accumulator tile into per-lane top-2.
// k is globally ascending (W ascending, rowmap (r&3)+8*(r>>2) ascending in r),
// so strict > keeps the lowest index on ties (argmin rule).
// Fast path: if the tile max can't beat the current best, only sv can change.
__device__ __forceinline__ void fold_tile(const f32x16& a, int W, int g,
                                          float& bv, float& sv, int& bi) {
    float M = max16(a);
    if (M >= bv) {
        #pragma unroll
        for (int r = 0; r < 16; r++) {
            float v = a[r];
            int k = (W << 5) + (r & 3) + ((r >> 2) << 3) + (g << 2);
            if (v > bv) { sv = bv; bv = v; bi = k; }
            else sv = fmaxf(sv, v);
        }
    } else {
        sv = fmaxf(sv, M);   // tile's other values are < M, can't be 2nd-best
    }
}

// Main: f16 MFMA similarity search, 32 px/wave, LDS-shared codebook stream,
// COUNTED-VMCNT PIPELINE (round-7).
// Round-6 post-mortem: spill fixed (WRITE 131.7 MB ideal, VGPR 128) but k_main
// stuck at 214 us vs the 82 us LDS-read floor -- __syncthreads() per granule
// compiles to s_waitcnt vmcnt(0)+s_barrier, draining the just-issued stage of
// g+1 and putting full L2 latency serially in every granule period (the guide's
// "never drain vmcnt to 0 in the main loop" anti-pattern, T3/T4).
// New schedule: granule = 8 ks-fragments (8 KB), 128 granules, RING OF 3
// buffers (24 KB LDS -> still 4 blocks/CU = 96 KB, zero grid tail). Per
// granule: issue stage(g+2) (2 gload_lds/wave) -> compute(g) (8 ds_read + 8
// MFMA) -> s_waitcnt vmcnt(2) (waits only for g+1, issued a FULL granule
// earlier; g+2's loads stay in flight across the barrier) -> raw s_barrier +
// sched_barrier(0). m201/m218-proven mechanism in plain HIP.
// Ring safety: stage(g+2) overwrites slot (g-1)%3, whose readers all passed
// the barrier at end of g-1 before any wave entered g. vmcnt is per-wave;
// each wave's vmcnt(2) + the barrier jointly publish all 16 KB... (8 KB) of
// granule g+1 before anyone reads it.
// Numerics: granule order H(ks0-7),H(ks8-15),L(ks0-7),L(ks8-15) per W -- the
// SAME MFMA chain order as round 6 (16xH then 16xL) -> bit-identical results.
__global__ __launch_bounds__(256, 2)
void k_main(const float* __restrict__ z, const float* __restrict__ wN,
            const half8* __restrict__ cbH, const half8* __restrict__ cbL,
            float* __restrict__ out) {
    __shared__ half8 sbuf[3][512];    // 3 x 8KB granule: [ks8][lane]

    int tid  = threadIdx.x;
    int lane = tid & 63, wv = tid >> 6;
    int g    = lane >> 5, l31 = lane & 31;
    int blk  = blockIdx.x;
    int b    = blk >> 5;                      // image (32 blocks of 128 px each)
    int wpx  = ((blk & 31) << 7) + (wv << 5); // this wave's pixel base in plane
    const float* zb = z + ((size_t)b << 20);

    // ---- prologue: stage granules 0 (H ks0-7) and 1 (H ks8-15) of W=0 ----
    #pragma unroll
    for (int i = 0; i < 2; i++) {
        int u = (wv << 1) + i;                // 0..7, wave-uniform
        stage16(cbH + (u << 6) + lane, &sbuf[0][u << 6]);
        stage16(cbH + ((u + 8) << 6) + lane, &sbuf[1][u << 6]);
    }

    // ---- setup: load 32 pixels x 256 ch, cast f16 (RNE), accumulate |z|^2 ----
    // Lane l holds channels {16ks + 8g + i} of pixel wpx + (l&31);
    // lane^32 holds the complementary channel half of the same pixel.
    half8 Bf[16];
    float np0 = 0.0f;
    #pragma unroll
    for (int ks = 0; ks < 16; ks++) {
        const float* zp = zb + ((size_t)((ks << 4) + (g << 3)) << 12) + wpx + l31;
        half8 h;
        float s = 0.0f;
        #pragma unroll
        for (int i = 0; i < 8; i++) {
            float v = zp[(size_t)i << 12];
            s += v * v;
            h[i] = (_Float16)v;
        }
        np0 += s;
        Bf[ks] = h;
    }
    __syncthreads();   // granules 0,1 staged (full drain once); waves synced

    // ---- main: 128 granules; granule G: W=G>>2, plane=(G>>1)&1, ksbase=(G&1)*8
    float bv0 = -3e38f, sv0 = -3e38f;
    int bi0 = 0;
    f32x16 acc = {};
    #pragma unroll 1
    for (int G = 0; G < 128; G++) {
        int slot = G % 3;
        if (G + 2 < 128) {
            int nG = G + 2;
            const half8* src = ((nG >> 1) & 1) ? (cbL + ((nG >> 2) << 10))
                                               : (cbH + ((nG >> 2) << 10));
            src += (nG & 1) << 9;             // ks8-15 half of the plane
            int ns = nG % 3;
            #pragma unroll
            for (int i = 0; i < 2; i++) {
                int u = (wv << 1) + i;
                stage16(src + (u << 6) + lane, &sbuf[ns][u << 6]);
            }
        }
        int ksb = (G & 1) << 3;
        #pragma unroll
        for (int k8 = 0; k8 < 8; k8++) {
            half8 A = sbuf[slot][(k8 << 6) + lane];
            acc = __builtin_amdgcn_mfma_f32_32x32x16_f16(A, Bf[ksb + k8], acc, 0, 0, 0);
        }
        if ((G & 3) == 3) {
            fold_tile(acc, G >> 2, g, bv0, sv0, bi0);
            #pragma unroll
            for (int r = 0; r < 16; r++) acc[r] = 0.0f;
        }
        // counted wait: g+1's stage (issued last iter) must be landed; g+2's
        // 2 loads stay in flight across the barrier. Never vmcnt(0) here.
        if (G + 2 < 128)      { asm volatile("s_waitcnt vmcnt(2)" ::: "memory"); }
        else if (G + 1 < 128) { asm volatile("s_waitcnt vmcnt(0)" ::: "memory"); }
        if (G + 1 < 128) {
            __builtin_amdgcn_s_barrier();
            __builtin_amdgcn_sched_barrier(0);
        }
    }

    // ---- merge lane pairs (lane ^ 32 holds the other row-half of same col) ----
    float BV0, SV0; int BI0;
    {
        float obv = __shfl_xor(bv0, 32), osv = __shfl_xor(sv0, 32);
        int obi = __shfl_xor(bi0, 32);
        if (obv > bv0 || (obv == bv0 && obi < bi0)) { BV0 = obv; BI0 = obi; SV0 = fmaxf(osv, bv0); }
        else                                        { BV0 = bv0; BI0 = bi0; SV0 = fmaxf(sv0, obv); }
    }
    float nn0 = np0 + __shfl_xor(np0, 32);

    // ---- idx + vq loss ----
    float dsum = 0.0f;
    if (lane < 32) {
        int fi = BI0;
        if (BV0 - SV0 < REFINE_TAU) fi += MARK;
        out[IDX_OFF + (b << 12) + wpx + lane] = (float)fi;
        float rinv = 1.0f / fmaxf(sqrtf(nn0), 1e-12f);
        dsum = 2.0f - 2.0f * BV0 * rinv;
    }
    #pragma unroll
    for (int off = 32; off > 0; off >>= 1) dsum += __shfl_xor(dsum, off);
    if (lane == 0) atomicAdd(out + VQ_OFF, dsum * VQ_SCALE);

    // ---- z_q write: lane pair (l, l^32) owns pixel wpx+l31; each lane streams
    //      its g-half (128 ch) of wN[bi] (L2/L1-hot); stores are two 128B
    //      segments per instruction ----
    const float4* wrow = reinterpret_cast<const float4*>(wN + ((size_t)BI0 << 8) + ((size_t)g << 7));
    size_t ob = ((size_t)b << 20) + ((size_t)g << 19) + (size_t)(wpx + l31);
    #pragma unroll 4
    for (int c4 = 0; c4 < 32; c4++) {
        float4 q = wrow[c4];
        out[ob + ((size_t)((c4 << 2) + 0) << 12)] = q.x;
        out[ob + ((size_t)((c4 << 2) + 1) << 12)] = q.y;
        out[ob + ((size_t)((c4 << 2) + 2) << 12)] = q.z;
        out[ob + ((size_t)((c4 << 2) + 3) << 12)] = q.w;
    }
}

// ---------------- k_refine: batched, parallel near-tie re-rank ----------------
// One chunk: P pixels re-ranked together. wT is streamed ONCE per chunk.
// All per-codeword dot chains keep the exact old fma order (c ascending) ->
// bit-identical ranking.
template<int P>
__device__ __forceinline__ void refine_chunk(
    int b, const int* q, const int* koldq, int done, int act,
    const float* __restrict__ z, const float* __restrict__ wT,
    float* __restrict__ out,
    float (*flz)[256], float (*rrs)[16], float* nn,
    float (*wredd)[4], int (*wredk)[4], int* knew_sh) {
    int tid = threadIdx.x;

    // load pixel columns (zeros for padded slots)
    #pragma unroll
    for (int p = 0; p < P; p++) {
        float v = 0.0f;
        if (p < act) {
            int hw = q[done + p] & 4095;
            v = z[((size_t)((b << 8) + tid) << 12) + hw];
        }
        flz[p][tid] = v;
    }
    __syncthreads();

    // numpy-exact norm: 16 accumulator chains per pixel, one thread each,
    // identical order to np_sumsq128 (j = chain, i ascending).
    if (tid < 16 * P) {
        int p = tid >> 4, w = tid & 15;
        const float* x = &flz[p][0];
        int base = ((w >> 3) << 7) + (w & 7);
        float r = mul_nofuse(x[base], x[base]);
        #pragma unroll
        for (int i = 1; i < 16; i++) {
            float xv = x[base + (i << 3)];
            r += mul_nofuse(xv, xv);
        }
        rrs[p][w] = r;
    }
    __syncthreads();
    if (tid < P) {
        const float* rp = rrs[tid];
        float s0 = ((rp[0] + rp[1]) + (rp[2] + rp[3])) + ((rp[4] + rp[5]) + (rp[6] + rp[7]));
        float s1 = ((rp[8] + rp[9]) + (rp[10] + rp[11])) + ((rp[12] + rp[13]) + (rp[14] + rp[15]));
        nn[tid] = fmaxf(sqrtf(s0 + s1), 1e-12f);
    }
    __syncthreads();
    #pragma unroll
    for (int p = 0; p < P; p++) flz[p][tid] = flz[p][tid] / nn[p];   // fv, IEEE div
    __syncthreads();

    // dot: thread t ranks k = t, t+256, t+512, t+768; wT read once per chunk.
    float a0[P], a1[P], a2[P], a3[P];
    #pragma unroll
    for (int p = 0; p < P; p++) { a0[p] = 0.f; a1[p] = 0.f; a2[p] = 0.f; a3[p] = 0.f; }
    #pragma unroll 1
    for (int c0 = 0; c0 < C_; c0 += 4) {
        f32x4 fz[P];
        #pragma unroll
        for (int p = 0; p < P; p++)
            fz[p] = *reinterpret_cast<const f32x4*>(&flz[p][c0]);
        #pragma unroll
        for (int j = 0; j < 4; j++) {
            const float* col = wT + ((c0 + j) << 10) + tid;
            float w0 = col[0], w1 = col[256], w2 = col[512], w3 = col[768];
            #pragma unroll
            for (int p = 0; p < P; p++) {
                float a = fz[p][j];
                a0[p] = fmaf(a, w0, a0[p]);
                a1[p] = fmaf(a, w1, a1[p]);
                a2[p] = fmaf(a, w2, a2[p]);
                a3[p] = fmaf(a, w3, a3[p]);
            }
        }
    }

    // per-thread fold (strict <, ascending k) + wave min + cross-wave min,
    // lowest index wins ties (same predicate as the old tree reduction).
    int lane = tid & 63, wv = tid >> 6;
    #pragma unroll
    for (int p = 0; p < P; p++) {
        float dbest = 1e30f; int kbest = 0;
        { float d = 2.0f - 2.0f * a0[p]; if (d < dbest) { dbest = d; kbest = tid;       } }
        { float d = 2.0f - 2.0f * a1[p]; if (d < dbest) { dbest = d; kbest = tid + 256; } }
        { float d = 2.0f - 2.0f * a2[p]; if (d < dbest) { dbest = d; kbest = tid + 512; } }
        { float d = 2.0f - 2.0f * a3[p]; if (d < dbest) { dbest = d; kbest = tid + 768; } }
        #pragma unroll
        for (int off = 32; off > 0; off >>= 1) {
            float d2 = __shfl_xor(dbest, off);
            int   k2 = __shfl_xor(kbest, off);
            if (d2 < dbest || (d2 == dbest && k2 < kbest)) { dbest = d2; kbest = k2; }
        }
        if (lane == 0) { wredd[p][wv] = dbest; wredk[p][wv] = kbest; }
    }
    __syncthreads();
    if (tid < P) {
        float dbest = wredd[tid][0]; int kbest = wredk[tid][0];
        #pragma unroll
        for (int w = 1; w < 4; w++) {
            float d2 = wredd[tid][w]; int k2 = wredk[tid][w];
            if (d2 < dbest || (d2 == dbest && k2 < kbest)) { dbest = d2; kbest = k2; }
        }
        knew_sh[tid] = kbest;
    }
    __syncthreads();

    // epilogue: clear marker, patch z_q + loss for flips (rare; old serial math)
    for (int p = 0; p < act; p++) {
        int n    = q[done + p];
        int kold = koldq[done + p];
        int knew = knew_sh[p];
        if (tid == 0) out[IDX_OFF + n] = (float)knew;
        if (knew != kold) {
            int hw = n & 4095;
            out[((size_t)((b << 8) + tid) << 12) + hw] = wT[(tid << 10) + knew];
            if (tid == 0) {
                float ao = 0.f, an = 0.f;
                for (int c = 0; c < C_; c++) {
                    ao = fmaf(flz[p][c], wT[(c << 10) + kold], ao);
                    an = fmaf(flz[p][c], wT[(c << 10) + knew], an);
                }
                atomicAdd(out + VQ_OFF, ((2.0f - 2.0f * an) - (2.0f - 2.0f * ao)) * VQ_SCALE);
            }
        }
    }
}

// 512 blocks; block g owns pixels [g*256,(g+1)*256) (same image b per strip,
// since 256 divides 4096) -- exclusive ownership, no cross-block races.
__global__ __launch_bounds__(256)
void k_refine(const float* __restrict__ z, const float* __restrict__ wT,
              float* __restrict__ out) {
    __shared__ float flz[8][256];
    __shared__ float rrs[8][16];
    __shared__ float nn[8];
    __shared__ float wredd[8][4];
    __shared__ int   wredk[8][4];
    __shared__ int   knew_sh[8];
    __shared__ int   q[256];
    __shared__ int   koldq[256];
    __shared__ int   wcnt[4];
    int tid  = threadIdx.x;
    int base = blockIdx.x << 8;
    int b    = base >> 12;

    // scan: ballot-compact the marked pixels of this strip (kold read here,
    // BEFORE any patch write -- ownership is exclusive so no other block
    // touches these idx entries).
    float fidx = out[IDX_OFF + base + tid];
    bool marked = fidx >= (float)MARK;
    unsigned long long mask = __ballot(marked);
    int lane = tid & 63, wv = tid >> 6;
    if (lane == 0) wcnt[wv] = __popcll(mask);
    __syncthreads();
    int off = 0;
    for (int w = 0; w < wv; w++) off += wcnt[w];
    if (marked) {
        int slot = off + __popcll(mask & ((1ull << lane) - 1ull));
        q[slot] = base + tid;
        koldq[slot] = (int)fidx - MARK;
    }
    __syncthreads();
    int cnt = wcnt[0] + wcnt[1] + wcnt[2] + wcnt[3];
    if (cnt == 0) return;

    int done = 0;
    while (done < cnt) {
        int rem = cnt - done;
        int act;
        if (rem >= 5) {
            act = rem > 8 ? 8 : rem;
            refine_chunk<8>(b, q, koldq, done, act, z, wT, out, flz, rrs, nn, wredd, wredk, knew_sh);
        } else if (rem >= 3) {
            act = rem;
            refine_chunk<4>(b, q, koldq, done, act, z, wT, out, flz, rrs, nn, wredd, wredk, knew_sh);
        } else if (rem == 2) {
            act = 2;
            refine_chunk<2>(b, q, koldq, done, act, z, wT, out, flz, rrs, nn, wredd, wredk, knew_sh);
        } else {
            act = 1;
            refine_chunk<1>(b, q, koldq, done, act, z, wT, out, flz, rrs, nn, wredd, wredk, knew_sh);
        }
        done += act;
        __syncthreads();   // flz/knew_sh reuse protection across chunks
    }
}

extern "C" void kernel_launch(void* const* d_in, const int* in_sizes, int n_in,
                              void* d_out, int out_size, void* d_ws, size_t ws_size,
                              hipStream_t stream) {
    const float* z = (const float*)d_in[0];   // (32,256,64,64) fp32
    const float* w = (const float*)d_in[1];   // (1024,256) fp32
    float* out = (float*)d_out;
    float* wT  = (float*)d_ws;                     // 1 MB
    float* wN  = wT + 262144;                      // 1 MB
    half8* cbH = (half8*)(wT + 524288);            // 512 KB
    half8* cbL = (half8*)(wT + 655360);            // 512 KB  (needs ws >= 3 MB)

    hipLaunchKernelGGL(k_normw,  dim3(16),   dim3(256), 0, stream, w, wT, wN, cbH, cbL, out);
    hipLaunchKernelGGL(k_topo,   dim3(256),  dim3(256), 0, stream, wT, out);
    hipLaunchKernelGGL(k_main,   dim3(1024), dim3(256), 0, stream, z, wN, cbH, cbL, out);
    hipLaunchKernelGGL(k_refine, dim3(512),  dim3(256), 0, stream, z, wT, out);
}

// Round 8
// 427.364 us; speedup vs baseline: 2.1388x; 2.1388x over previous
//
#include <hip/hip_runtime.h>
#include <cstdint>
#include <cstddef>

// Problem constants
#define C_ 256
#define HW_ 4096
#define N_ 131072          // B*H*W = 32*64*64
#define K_ 1024
#define VQ_OFF   33554432  // after z_q (32*256*64*64)
#define IDX_OFF  33554433
#define TOPO_OFF 33685505  // IDX_OFF + 131072
#define VQ_SCALE (1.25f / 33554432.0f)   // (1+0.25) * mean over B*H*W*C elements
#define REFINE_TAU 4e-3f   // unnormalized-dot gap below which we np-emulate.
                           // single-plane f16 pair-gap sigma ~2.8e-4 -> 14 sigma.
#define MARK 2048          // idx marker for flagged pixels (true idx < 1024)

typedef _Float16 half8  __attribute__((ext_vector_type(8)));
typedef float    f32x16 __attribute__((ext_vector_type(16)));
typedef float    f32x4  __attribute__((ext_vector_type(4)));

// Workspace layout (floats):
//   wT  @ 0        [256][1024] fp32  (column-major codebook, for topo/refine)
//   wN  @ 262144   [1024][256] fp32  (row-major codebook, for z_q gather)
//   cbH @ 524288   f16 plane in MFMA-fragment-linear order (512 KB)
// Fragment order: idx = ((cw>>5)*16 + (c>>4))*64 + (cw&31) + 32*((c>>3)&1),
// element i = c&7  -> a wave's A-fragment load is cb[(W*16+ks)*64 + lane],
// one fully-coalesced 1KB dwordx4 per wave.
//
// ROUND-7 POST-MORTEM (counted-vmcnt ring-3 attempt): WRITE_SIZE +65.5 MB =
// 131072 threads x 512 B = Bf[16] spilled (VGPR fell to 100); FETCH +800 MB =
// scratch re-reads of Bf every granule. The sched_barrier(0)-pinned regions +
// persistent acc pushed the allocator into spilling the resident pixel
// fragments -> kernel became HBM-bound on its own spill (696 us). Reverted to
// the round-6 schedule (verified spill-free at 214 us) and instead HALVED the
// work: single-plane f16 codebook (drop the lo-correction plane). Ranking
// error stays 14 sigma inside REFINE_TAU's guard band; flagged pixels are
// re-ranked exactly in fp32 by k_refine.

// fp32 multiply with an anti-contraction barrier: numpy rounds x*x BEFORE the
// pairwise add; fp-contract would fuse mul+add into fma (different rounding).
__device__ __forceinline__ float mul_nofuse(float a, float b) {
    float t = a * b;
    asm volatile("" : "+v"(t));
    return t;
}

// numpy pairwise_sum of squares, n=128 (8-accumulator unroll, numpy combine order)
__device__ __forceinline__ float np_sumsq128(const float* x) {
    float r[8];
    #pragma unroll
    for (int j = 0; j < 8; j++) r[j] = mul_nofuse(x[j], x[j]);
    for (int i = 8; i < 128; i += 8) {
        #pragma unroll
        for (int j = 0; j < 8; j++) r[j] += mul_nofuse(x[i + j], x[i + j]);
    }
    return ((r[0] + r[1]) + (r[2] + r[3])) + ((r[4] + r[5]) + (r[6] + r[7]));
}

__device__ __forceinline__ float np_norm256(const float* x) {
    float ss = np_sumsq128(x) + np_sumsq128(x + 128);
    return sqrtf(ss);
}

// async global->LDS, 16B per lane. dest: wave-uniform base (+ lane*16 by HW).
__device__ __forceinline__ void stage16(const half8* g, half8* l) {
    __builtin_amdgcn_global_load_lds(
        (const __attribute__((address_space(1))) void*)g,
        (__attribute__((address_space(3))) void*)l, 16, 0, 0);
}

// Normalize codebook rows (numpy-emulated norms, true division).
// Emits: wT[c][k] fp32, wN[k][c] fp32, and the f16 fragment plane for MFMA.
__global__ __launch_bounds__(256)
void k_normw(const float* __restrict__ w, float* __restrict__ wT,
             float* __restrict__ wN, half8* __restrict__ cbH,
             float* __restrict__ out) {
    __shared__ float lw[64][257];
    __shared__ float nrm_sh[64];
    int tid = threadIdx.x;
    if (blockIdx.x == 0 && tid == 0) {
        out[VQ_OFF] = 0.0f;
        out[TOPO_OFF] = 0.0f;
    }
    int r0 = blockIdx.x << 6;
    #pragma unroll
    for (int it = 0; it < 64; it++) {
        int f = (it << 8) + tid;       // 0..16383
        int row = f >> 8, c = f & 255;
        lw[row][c] = w[((size_t)(r0 + row) << 8) + c];
    }
    __syncthreads();
    if (tid < 64) nrm_sh[tid] = fmaxf(np_norm256(&lw[tid][0]), 1e-12f);
    __syncthreads();
    int rr = tid & 63, cg = tid >> 6;
    float nr = nrm_sh[rr];
    for (int c = cg; c < C_; c += 4) {
        wT[(c << 10) + r0 + rr] = lw[rr][c] / nr;
    }
    // wN row-major + f16 fragment plane (RNE cast of the fp32 normalized value)
    int cw = r0 + rr;
    int cwblk = cw >> 5, lrow = cw & 31;
    #pragma unroll
    for (int o8 = cg; o8 < 32; o8 += 4) {   // 8 octets of channels per thread
        int c0 = o8 << 3;
        half8 H;
        float vv[8];
        #pragma unroll
        for (int i = 0; i < 8; i++) {
            float v = lw[rr][c0 + i] / nr;
            vv[i] = v;
            H[i] = (_Float16)v;             // RNE
        }
        float4* wnp = reinterpret_cast<float4*>(wN + ((size_t)cw << 8) + c0);
        wnp[0] = make_float4(vv[0], vv[1], vv[2], vv[3]);
        wnp[1] = make_float4(vv[4], vv[5], vv[6], vv[7]);
        int fidx = ((cwblk << 4) + (o8 >> 1)) * 64 + lrow + ((o8 & 1) << 5);
        cbH[fidx] = H;
    }
}

// Topology smoothness loss over the 32x32 grid of normalized codewords.
__global__ void k_topo(const float* __restrict__ wT, float* __restrict__ out) {
    const float W12 = 0.35f / (32.0f * 31.0f * 256.0f);
    const float W34 = 0.35f / (32.0f * 256.0f);
    float acc = 0.0f;
    int base = (blockIdx.x << 8) + threadIdx.x;
    #pragma unroll
    for (int i = 0; i < 4; i++) {
        int e = base + (i << 16);      // e = c*1024 + k, coalesced over wT
        int k = e & 1023;
        int ii = k >> 5, jj = k & 31;
        float v = wT[e];
        if (jj < 31)  { float d = wT[e + 1]   - v; acc += d * d * W12; }
        if (ii < 31)  { float d = wT[e + 32]  - v; acc += d * d * W12; }
        if (jj == 31) { float d = wT[e - 31]  - v; acc += d * d * W34; }
        if (ii == 31) { float d = wT[e - 992] - v; acc += d * d * W34; }
    }
    for (int off = 32; off > 0; off >>= 1) acc += __shfl_xor(acc, off);
    __shared__ float red[4];
    if ((threadIdx.x & 63) == 0) red[threadIdx.x >> 6] = acc;
    __syncthreads();
    if (threadIdx.x == 0) atomicAdd(out + TOPO_OFF, red[0] + red[1] + red[2] + red[3]);
}

// 16-value tree max (all literal indices).
__device__ __forceinline__ float max16(const f32x16& a) {
    float m0 = fmaxf(fmaxf(a[0], a[1]),  fmaxf(a[2], a[3]));
    float m1 = fmaxf(fmaxf(a[4], a[5]),  fmaxf(a[6], a[7]));
    float m2 = fmaxf(fmaxf(a[8], a[9]),  fmaxf(a[10], a[11]));
    float m3 = fmaxf(fmaxf(a[12], a[13]), fmaxf(a[14], a[15]));
    return fmaxf(fmaxf(m0, m1), fmaxf(m2, m3));
}

// Fold one 32x32 accumulator tile into per-lane top-2.
// k is globally ascending (W ascending, rowmap (r&3)+8*(r>>2) ascending in r),
// so strict > keeps the lowest index on ties (argmin rule).
// Fast path: if the tile max can't beat the current best, only sv can change.
__device__ __forceinline__ void fold_tile(const f32x16& a, int W, int g,
                                          float& bv, float& sv, int& bi) {
    float M = max16(a);
    if (M >= bv) {
        #pragma unroll
        for (int r = 0; r < 16; r++) {
            float v = a[r];
            int k = (W << 5) + (r & 3) + ((r >> 2) << 3) + (g << 2);
            if (v > bv) { sv = bv; bv = v; bi = k; }
            else sv = fmaxf(sv, v);
        }
    } else {
        sv = fmaxf(sv, M);   // tile's other values are < M, can't be 2nd-best
    }
}

// Main: single-plane f16 MFMA similarity search, 32 px/wave, LDS-shared
// codebook stream (round-6 verified schedule, half the granules).
// Block = 4 waves x 32 px = 128 px; grid 1024 = exactly 4 blocks/CU.
// Granule = the f16 plane of one 32-codeword block = 16 KB; ring of 2 =
// 32 KB LDS -> 4 blocks/CU (128 KB), 16 waves/CU. 32 granules (vs 64 dual-
// plane in round 6): MFMA floor 27.5 us, LDS-read floor 41 us, stage 256 MB.
// __launch_bounds__(256,2): allocator caps at 128 VGPR (4-waves tier);
// Bf(64)+acc(16)+temps ~110 fits, zero spill (round-6 verified; round-5's
// (256,4) spilled at the 64-VGPR tier, round-7's pinned-schedule variant
// spilled Bf at VGPR=100 -- both showed the WRITE_SIZE inflation signature).
// Numerics: acc = zh*wh (z and w both RNE f16). Unnormalized-dot pair-gap
// error sigma ~2.8e-4; REFINE_TAU=4e-3 = 14 sigma -> near-ties all flagged,
// exact fp32 re-rank in k_refine. vq_loss shift ~1e-7.
__global__ __launch_bounds__(256, 2)
void k_main(const float* __restrict__ z, const float* __restrict__ wN,
            const half8* __restrict__ cbH, float* __restrict__ out) {
    __shared__ half8 sbuf[2][1024];   // 2 x 16KB granule: [ks][lane]

    int tid  = threadIdx.x;
    int lane = tid & 63, wv = tid >> 6;
    int g    = lane >> 5, l31 = lane & 31;
    int blk  = blockIdx.x;
    int b    = blk >> 5;                      // image (32 blocks of 128 px each)
    int wpx  = ((blk & 31) << 7) + (wv << 5); // this wave's pixel base in plane
    const float* zb = z + ((size_t)b << 20);

    // ---- prologue: stage granule W=0, then load pixels ----
    #pragma unroll
    for (int i = 0; i < 4; i++) {
        int u = (wv << 2) + i;                // 0..15, wave-uniform
        stage16(cbH + (u << 6) + lane, &sbuf[0][u << 6]);
    }

    // ---- setup: load 32 pixels x 256 ch, cast f16 (RNE), accumulate |z|^2 ----
    // Lane l holds channels {16ks + 8g + i} of pixel wpx + (l&31);
    // lane^32 holds the complementary channel half of the same pixel.
    half8 Bf[16];
    float np0 = 0.0f;
    #pragma unroll
    for (int ks = 0; ks < 16; ks++) {
        const float* zp = zb + ((size_t)((ks << 4) + (g << 3)) << 12) + wpx + l31;
        half8 h;
        float s = 0.0f;
        #pragma unroll
        for (int i = 0; i < 8; i++) {
            float v = zp[(size_t)i << 12];
            s += v * v;
            h[i] = (_Float16)v;
        }
        np0 += s;
        Bf[ks] = h;
    }
    __syncthreads();   // granule 0 staged (vmcnt drained) for all waves

    // ---- main: 32 codeword-block granules; stage W+1 while computing W ----
    float bv0 = -3e38f, sv0 = -3e38f;
    int bi0 = 0;
    #pragma unroll 1
    for (int W = 0; W < 32; W++) {
        int bsel = W & 1;
        if (W < 31) {
            const half8* src = cbH + ((W + 1) << 10);
            #pragma unroll
            for (int i = 0; i < 4; i++) {
                int u = (wv << 2) + i;
                stage16(src + (u << 6) + lane, &sbuf[bsel ^ 1][u << 6]);
            }
        }
        f32x16 acc = {};
        #pragma unroll
        for (int ks = 0; ks < 16; ks++) {
            half8 A = sbuf[bsel][(ks << 6) + lane];
            acc = __builtin_amdgcn_mfma_f32_32x32x16_f16(A, Bf[ks], acc, 0, 0, 0);
        }
        __syncthreads();   // waves done reading sbuf[bsel]; stage(W+1) landed
        fold_tile(acc, W, g, bv0, sv0, bi0);
    }

    // ---- merge lane pairs (lane ^ 32 holds the other row-half of same col) ----
    float BV0, SV0; int BI0;
    {
        float obv = __shfl_xor(bv0, 32), osv = __shfl_xor(sv0, 32);
        int obi = __shfl_xor(bi0, 32);
        if (obv > bv0 || (obv == bv0 && obi < bi0)) { BV0 = obv; BI0 = obi; SV0 = fmaxf(osv, bv0); }
        else                                        { BV0 = bv0; BI0 = bi0; SV0 = fmaxf(sv0, obv); }
    }
    float nn0 = np0 + __shfl_xor(np0, 32);

    // ---- idx + vq loss ----
    float dsum = 0.0f;
    if (lane < 32) {
        int fi = BI0;
        if (BV0 - SV0 < REFINE_TAU) fi += MARK;
        out[IDX_OFF + (b << 12) + wpx + lane] = (float)fi;
        float rinv = 1.0f / fmaxf(sqrtf(nn0), 1e-12f);
        dsum = 2.0f - 2.0f * BV0 * rinv;
    }
    #pragma unroll
    for (int off = 32; off > 0; off >>= 1) dsum += __shfl_xor(dsum, off);
    if (lane == 0) atomicAdd(out + VQ_OFF, dsum * VQ_SCALE);

    // ---- z_q write: lane pair (l, l^32) owns pixel wpx+l31; each lane streams
    //      its g-half (128 ch) of wN[bi] (L2/L1-hot); stores are two 128B
    //      segments per instruction ----
    const float4* wrow = reinterpret_cast<const float4*>(wN + ((size_t)BI0 << 8) + ((size_t)g << 7));
    size_t ob = ((size_t)b << 20) + ((size_t)g << 19) + (size_t)(wpx + l31);
    #pragma unroll 4
    for (int c4 = 0; c4 < 32; c4++) {
        float4 q = wrow[c4];
        out[ob + ((size_t)((c4 << 2) + 0) << 12)] = q.x;
        out[ob + ((size_t)((c4 << 2) + 1) << 12)] = q.y;
        out[ob + ((size_t)((c4 << 2) + 2) << 12)] = q.z;
        out[ob + ((size_t)((c4 << 2) + 3) << 12)] = q.w;
    }
}

// ---------------- k_refine: batched, parallel near-tie re-rank ----------------
// One chunk: P pixels re-ranked together. wT is streamed ONCE per chunk.
// All per-codeword dot chains keep the exact old fma order (c ascending) ->
// bit-identical ranking.
template<int P>
__device__ __forceinline__ void refine_chunk(
    int b, const int* q, const int* koldq, int done, int act,
    const float* __restrict__ z, const float* __restrict__ wT,
    float* __restrict__ out,
    float (*flz)[256], float (*rrs)[16], float* nn,
    float (*wredd)[4], int (*wredk)[4], int* knew_sh) {
    int tid = threadIdx.x;

    // load pixel columns (zeros for padded slots)
    #pragma unroll
    for (int p = 0; p < P; p++) {
        float v = 0.0f;
        if (p < act) {
            int hw = q[done + p] & 4095;
            v = z[((size_t)((b << 8) + tid) << 12) + hw];
        }
        flz[p][tid] = v;
    }
    __syncthreads();

    // numpy-exact norm: 16 accumulator chains per pixel, one thread each,
    // identical order to np_sumsq128 (j = chain, i ascending).
    if (tid < 16 * P) {
        int p = tid >> 4, w = tid & 15;
        const float* x = &flz[p][0];
        int base = ((w >> 3) << 7) + (w & 7);
        float r = mul_nofuse(x[base], x[base]);
        #pragma unroll
        for (int i = 1; i < 16; i++) {
            float xv = x[base + (i << 3)];
            r += mul_nofuse(xv, xv);
        }
        rrs[p][w] = r;
    }
    __syncthreads();
    if (tid < P) {
        const float* rp = rrs[tid];
        float s0 = ((rp[0] + rp[1]) + (rp[2] + rp[3])) + ((rp[4] + rp[5]) + (rp[6] + rp[7]));
        float s1 = ((rp[8] + rp[9]) + (rp[10] + rp[11])) + ((rp[12] + rp[13]) + (rp[14] + rp[15]));
        nn[tid] = fmaxf(sqrtf(s0 + s1), 1e-12f);
    }
    __syncthreads();
    #pragma unroll
    for (int p = 0; p < P; p++) flz[p][tid] = flz[p][tid] / nn[p];   // fv, IEEE div
    __syncthreads();

    // dot: thread t ranks k = t, t+256, t+512, t+768; wT read once per chunk.
    float a0[P], a1[P], a2[P], a3[P];
    #pragma unroll
    for (int p = 0; p < P; p++) { a0[p] = 0.f; a1[p] = 0.f; a2[p] = 0.f; a3[p] = 0.f; }
    #pragma unroll 1
    for (int c0 = 0; c0 < C_; c0 += 4) {
        f32x4 fz[P];
        #pragma unroll
        for (int p = 0; p < P; p++)
            fz[p] = *reinterpret_cast<const f32x4*>(&flz[p][c0]);
        #pragma unroll
        for (int j = 0; j < 4; j++) {
            const float* col = wT + ((c0 + j) << 10) + tid;
            float w0 = col[0], w1 = col[256], w2 = col[512], w3 = col[768];
            #pragma unroll
            for (int p = 0; p < P; p++) {
                float a = fz[p][j];
                a0[p] = fmaf(a, w0, a0[p]);
                a1[p] = fmaf(a, w1, a1[p]);
                a2[p] = fmaf(a, w2, a2[p]);
                a3[p] = fmaf(a, w3, a3[p]);
            }
        }
    }

    // per-thread fold (strict <, ascending k) + wave min + cross-wave min,
    // lowest index wins ties (same predicate as the old tree reduction).
    int lane = tid & 63, wv = tid >> 6;
    #pragma unroll
    for (int p = 0; p < P; p++) {
        float dbest = 1e30f; int kbest = 0;
        { float d = 2.0f - 2.0f * a0[p]; if (d < dbest) { dbest = d; kbest = tid;       } }
        { float d = 2.0f - 2.0f * a1[p]; if (d < dbest) { dbest = d; kbest = tid + 256; } }
        { float d = 2.0f - 2.0f * a2[p]; if (d < dbest) { dbest = d; kbest = tid + 512; } }
        { float d = 2.0f - 2.0f * a3[p]; if (d < dbest) { dbest = d; kbest = tid + 768; } }
        #pragma unroll
        for (int off = 32; off > 0; off >>= 1) {
            float d2 = __shfl_xor(dbest, off);
            int   k2 = __shfl_xor(kbest, off);
            if (d2 < dbest || (d2 == dbest && k2 < kbest)) { dbest = d2; kbest = k2; }
        }
        if (lane == 0) { wredd[p][wv] = dbest; wredk[p][wv] = kbest; }
    }
    __syncthreads();
    if (tid < P) {
        float dbest = wredd[tid][0]; int kbest = wredk[tid][0];
        #pragma unroll
        for (int w = 1; w < 4; w++) {
            float d2 = wredd[tid][w]; int k2 = wredk[tid][w];
            if (d2 < dbest || (d2 == dbest && k2 < kbest)) { dbest = d2; kbest = k2; }
        }
        knew_sh[tid] = kbest;
    }
    __syncthreads();

    // epilogue: clear marker, patch z_q + loss for flips (rare; old serial math)
    for (int p = 0; p < act; p++) {
        int n    = q[done + p];
        int kold = koldq[done + p];
        int knew = knew_sh[p];
        if (tid == 0) out[IDX_OFF + n] = (float)knew;
        if (knew != kold) {
            int hw = n & 4095;
            out[((size_t)((b << 8) + tid) << 12) + hw] = wT[(tid << 10) + knew];
            if (tid == 0) {
                float ao = 0.f, an = 0.f;
                for (int c = 0; c < C_; c++) {
                    ao = fmaf(flz[p][c], wT[(c << 10) + kold], ao);
                    an = fmaf(flz[p][c], wT[(c << 10) + knew], an);
                }
                atomicAdd(out + VQ_OFF, ((2.0f - 2.0f * an) - (2.0f - 2.0f * ao)) * VQ_SCALE);
            }
        }
    }
}

// 512 blocks; block g owns pixels [g*256,(g+1)*256) (same image b per strip,
// since 256 divides 4096) -- exclusive ownership, no cross-block races.
__global__ __launch_bounds__(256)
void k_refine(const float* __restrict__ z, const float* __restrict__ wT,
              float* __restrict__ out) {
    __shared__ float flz[8][256];
    __shared__ float rrs[8][16];
    __shared__ float nn[8];
    __shared__ float wredd[8][4];
    __shared__ int   wredk[8][4];
    __shared__ int   knew_sh[8];
    __shared__ int   q[256];
    __shared__ int   koldq[256];
    __shared__ int   wcnt[4];
    int tid  = threadIdx.x;
    int base = blockIdx.x << 8;
    int b    = base >> 12;

    // scan: ballot-compact the marked pixels of this strip (kold read here,
    // BEFORE any patch write -- ownership is exclusive so no other block
    // touches these idx entries).
    float fidx = out[IDX_OFF + base + tid];
    bool marked = fidx >= (float)MARK;
    unsigned long long mask = __ballot(marked);
    int lane = tid & 63, wv = tid >> 6;
    if (lane == 0) wcnt[wv] = __popcll(mask);
    __syncthreads();
    int off = 0;
    for (int w = 0; w < wv; w++) off += wcnt[w];
    if (marked) {
        int slot = off + __popcll(mask & ((1ull << lane) - 1ull));
        q[slot] = base + tid;
        koldq[slot] = (int)fidx - MARK;
    }
    __syncthreads();
    int cnt = wcnt[0] + wcnt[1] + wcnt[2] + wcnt[3];
    if (cnt == 0) return;

    int done = 0;
    while (done < cnt) {
        int rem = cnt - done;
        int act;
        if (rem >= 5) {
            act = rem > 8 ? 8 : rem;
            refine_chunk<8>(b, q, koldq, done, act, z, wT, out, flz, rrs, nn, wredd, wredk, knew_sh);
        } else if (rem >= 3) {
            act = rem;
            refine_chunk<4>(b, q, koldq, done, act, z, wT, out, flz, rrs, nn, wredd, wredk, knew_sh);
        } else if (rem == 2) {
            act = 2;
            refine_chunk<2>(b, q, koldq, done, act, z, wT, out, flz, rrs, nn, wredd, wredk, knew_sh);
        } else {
            act = 1;
            refine_chunk<1>(b, q, koldq, done, act, z, wT, out, flz, rrs, nn, wredd, wredk, knew_sh);
        }
        done += act;
        __syncthreads();   // flz/knew_sh reuse protection across chunks
    }
}

extern "C" void kernel_launch(void* const* d_in, const int* in_sizes, int n_in,
                              void* d_out, int out_size, void* d_ws, size_t ws_size,
                              hipStream_t stream) {
    const float* z = (const float*)d_in[0];   // (32,256,64,64) fp32
    const float* w = (const float*)d_in[1];   // (1024,256) fp32
    float* out = (float*)d_out;
    float* wT  = (float*)d_ws;                     // 1 MB
    float* wN  = wT + 262144;                      // 1 MB
    half8* cbH = (half8*)(wT + 524288);            // 512 KB (needs ws >= 2.5 MB)

    hipLaunchKernelGGL(k_normw,  dim3(16),   dim3(256), 0, stream, w, wT, wN, cbH, out);
    hipLaunchKernelGGL(k_topo,   dim3(256),  dim3(256), 0, stream, wT, out);
    hipLaunchKernelGGL(k_main,   dim3(1024), dim3(256), 0, stream, z, wN, cbH, out);
    hipLaunchKernelGGL(k_refine, dim3(512),  dim3(256), 0, stream, z, wT, out);
}